// Round 1
// baseline (1608.038 us; speedup 1.0000x reference)
//
#include <hip/hip_runtime.h>

#define SEQ   1024
#define BATCH 8192
#define NIN   3
#define HID   50
#define G4    200   // 4*HID
#define NT    13    // N tiles of 16 (208 cols, 200 used)
#define BT    16    // batch rows per block
#define KP    72    // h row stride in ushorts (144 B: 16B-aligned, 2-way banks)

typedef __attribute__((ext_vector_type(8))) short short8_t;  // 8 bf16
typedef __attribute__((ext_vector_type(4))) float f32x4;

__device__ __forceinline__ ushort f2bf(float x){
  union { float f; unsigned u; } v; v.f = x;
  unsigned r = v.u + 0x7FFFu + ((v.u >> 16) & 1u);  // RNE
  return (ushort)(r >> 16);
}
__device__ __forceinline__ float bf2f(ushort b){
  union { float f; unsigned u; } v; v.u = ((unsigned)b) << 16;
  return v.f;
}
__device__ __forceinline__ float sigm(float xv){
  return __builtin_amdgcn_rcpf(1.0f + __builtin_amdgcn_exp2f(-1.44269504f * xv));
}
__device__ __forceinline__ float tanh_f(float xv){
  // tanh(x) = 1 - 2/(1+e^{2x})
  return 1.0f - 2.0f * __builtin_amdgcn_rcpf(1.0f + __builtin_amdgcn_exp2f(2.88539008f * xv));
}

__global__ __launch_bounds__(256, 2)
void lstm_fused(const float* __restrict__ x,
                const float* __restrict__ W_ih,
                const float* __restrict__ W_hh,
                const float* __restrict__ b_ih,
                const float* __restrict__ b_hh,
                const float* __restrict__ fc_w,
                const float* __restrict__ fc_b,
                float* __restrict__ out)
{
  __shared__ __align__(16) ushort h_hi[BT][KP];   // h as bf16 (hi part), K-padded with zeros
  __shared__ __align__(16) ushort h_lo[BT][KP];   // bf16 residual of h
  __shared__ float gate_lds[BT][NT*16];           // fp32 gate preactivations
  __shared__ float xx[BT][NIN];                   // x_t staging
  __shared__ float hf[BT][HID];                   // final-step fp32 h

  const int tid  = threadIdx.x;
  const int wid  = tid >> 6;
  const int lane = tid & 63;
  const int r16  = lane & 15;   // MFMA: A-row / B-col / D-col
  const int grp  = lane >> 4;   // MFMA lane group
  const int b0   = blockIdx.x * BT;

  // ---- one-time: W_hh -> per-wave register B-fragments (bf16), W_ih/bias per lane ----
  // B operand: Bop[k][n] = W_hh[n][k]; lane holds k = kh*32 + grp*8 + i, n = tile*16 + r16
  short8_t Bf[4][2];
  float wih[4][3];
  float bsum[4];
  #pragma unroll
  for (int it = 0; it < 4; ++it) {
    int tile = wid + 4*it;                 // waves own tiles {w, w+4, w+8, (w+12)}
    int g = tile*16 + r16;
    bool gok = (tile < NT) && (g < G4);
    #pragma unroll
    for (int kh = 0; kh < 2; ++kh) {
      short8_t f;
      #pragma unroll
      for (int i = 0; i < 8; ++i) {
        int k = kh*32 + grp*8 + i;
        float w = (gok && k < HID) ? W_hh[g*HID + k] : 0.0f;
        f[i] = (short)f2bf(w);
      }
      Bf[it][kh] = f;
    }
    #pragma unroll
    for (int i = 0; i < 3; ++i) wih[it][i] = gok ? W_ih[g*NIN + i] : 0.0f;
    bsum[it] = gok ? (b_ih[g] + b_hh[g]) : 0.0f;
  }

  // ---- init h (zeros, incl. K padding 50..71) ----
  for (int i = tid; i < BT*KP/2; i += 256) {
    ((unsigned*)h_hi)[i] = 0u;
    ((unsigned*)h_lo)[i] = 0u;
  }

  float c[4] = {0.f, 0.f, 0.f, 0.f};

  for (int t = 0; t < SEQ; ++t) {
    // stage x_t (48 consecutive floats)
    if (tid < BT*NIN)
      ((float*)xx)[tid] = x[((size_t)t*BATCH + b0)*NIN + tid];
    __syncthreads();   // h (prev step) + x ready

    // x values for this lane's D-rows (b = grp*4 + i)
    float xr[4][3];
    #pragma unroll
    for (int i = 0; i < 4; ++i)
      #pragma unroll
      for (int ii = 0; ii < 3; ++ii)
        xr[i][ii] = xx[grp*4 + i][ii];

    // A fragments: A[row = r16][k = kh*32 + grp*8 + i]
    const short8_t a0h = *(const short8_t*)&h_hi[r16][grp*8];
    const short8_t a1h = *(const short8_t*)&h_hi[r16][32 + grp*8];
    const short8_t a0l = *(const short8_t*)&h_lo[r16][grp*8];
    const short8_t a1l = *(const short8_t*)&h_lo[r16][32 + grp*8];

    #pragma unroll
    for (int it = 0; it < 4; ++it) {
      int tile = wid + 4*it;
      if (tile < NT) {
        f32x4 acc;
        // C-init = bias + x * W_ih^T  (row b = grp*4+i, col g = tile*16+r16)
        #pragma unroll
        for (int i = 0; i < 4; ++i)
          acc[i] = bsum[it] + wih[it][0]*xr[i][0] + wih[it][1]*xr[i][1] + wih[it][2]*xr[i][2];
        acc = __builtin_amdgcn_mfma_f32_16x16x32_bf16(a0l, Bf[it][0], acc, 0, 0, 0);
        acc = __builtin_amdgcn_mfma_f32_16x16x32_bf16(a1l, Bf[it][1], acc, 0, 0, 0);
        acc = __builtin_amdgcn_mfma_f32_16x16x32_bf16(a0h, Bf[it][0], acc, 0, 0, 0);
        acc = __builtin_amdgcn_mfma_f32_16x16x32_bf16(a1h, Bf[it][1], acc, 0, 0, 0);
        // D: row = grp*4+i (batch), col = r16 (gate within tile)
        #pragma unroll
        for (int i = 0; i < 4; ++i)
          gate_lds[grp*4 + i][tile*16 + r16] = acc[i];
      }
    }
    __syncthreads();   // gates ready

    // ---- elementwise update: 800 (b,j) items, c in registers ----
    #pragma unroll
    for (int k = 0; k < 4; ++k) {
      int item = tid + 256*k;
      if (item < BT*HID) {
        int b = item / HID;
        int j = item - b*HID;
        float pi = gate_lds[b][j];
        float pf = gate_lds[b][HID   + j];
        float pg = gate_lds[b][2*HID + j];
        float po = gate_lds[b][3*HID + j];
        float si = sigm(pi), sf = sigm(pf), sg = tanh_f(pg), so = sigm(po);
        float cn = sf*c[k] + si*sg;
        c[k] = cn;
        float h = so * tanh_f(cn);
        ushort hb = f2bf(h);
        h_hi[b][j] = hb;
        h_lo[b][j] = f2bf(h - bf2f(hb));
        if (t == SEQ-1) hf[b][j] = h;
      }
    }
    // next iteration's top barrier separates h writes from A-frag reads
  }

  __syncthreads();
  // ---- epilogue: out[b] = fc_w . h_final[b] + fc_b ----
  if (tid < BT) {
    float s = fc_b[0];
    #pragma unroll
    for (int j = 0; j < HID; ++j) s += fc_w[j] * hf[tid][j];
    out[b0 + tid] = s;
  }
}

extern "C" void kernel_launch(void* const* d_in, const int* in_sizes, int n_in,
                              void* d_out, int out_size, void* d_ws, size_t ws_size,
                              hipStream_t stream)
{
  const float* x    = (const float*)d_in[0];
  const float* W_ih = (const float*)d_in[1];
  const float* W_hh = (const float*)d_in[2];
  const float* b_ih = (const float*)d_in[3];
  const float* b_hh = (const float*)d_in[4];
  const float* fc_w = (const float*)d_in[5];
  const float* fc_b = (const float*)d_in[6];
  lstm_fused<<<BATCH/BT, 256, 0, stream>>>(x, W_ih, W_hh, b_ih, b_hh, fc_w, fc_b,
                                           (float*)d_out);
}